// Round 1
// baseline (846.623 us; speedup 1.0000x reference)
//
#include <hip/hip_runtime.h>
#include <math.h>

#define N_NODES  100000
#define N_EDGES  3200000
#define K_IN     1433
#define NH       16
#define NO       7

#define TK       16
#define NC       ((K_IN + TK - 1) / TK)   // 90 chunks
#define GROWS    256                       // rows per block
#define PADK     (TK + 1)                  // 17 -> 2-way LDS conflicts only
#define NBLK     ((N_NODES + GROWS - 1) / GROWS)  // 391

// ---------------- K1: degree counts ----------------
__global__ void k_degrees(const int* __restrict__ src, const int* __restrict__ dst,
                          int* __restrict__ deg_out, int* __restrict__ deg_in) {
    int i = blockIdx.x * blockDim.x + threadIdx.x;
    int stride = gridDim.x * blockDim.x;
    for (; i < N_EDGES; i += stride) {
        atomicAdd(&deg_out[src[i]], 1);
        atomicAdd(&deg_in[dst[i]], 1);
    }
}

// ---------------- K2a: per-block sums of deg_in ----------------
__global__ void k_bsum(const int* __restrict__ deg_in, int* __restrict__ bsum) {
    int t = threadIdx.x;
    int i = blockIdx.x * 256 + t;
    int v = (i < N_NODES) ? deg_in[i] : 0;
#pragma unroll
    for (int o = 1; o < 64; o <<= 1) v += __shfl_xor(v, o);
    __shared__ int ws[4];
    if ((t & 63) == 0) ws[t >> 6] = v;
    __syncthreads();
    if (t == 0) bsum[blockIdx.x] = ws[0] + ws[1] + ws[2] + ws[3];
}

// ---------------- K2b: exclusive scan of block sums (1 block) ----------------
__global__ void k_scan(const int* __restrict__ bsum, int* __restrict__ boff) {
    __shared__ int s[512];
    int t = threadIdx.x;
    int my = (t < NBLK) ? bsum[t] : 0;
    s[t] = my;
    __syncthreads();
    for (int o = 1; o < 512; o <<= 1) {
        int v = (t >= o) ? s[t - o] : 0;
        __syncthreads();
        s[t] += v;
        __syncthreads();
    }
    if (t < NBLK) boff[t] = s[t] - my;   // exclusive
}

// ---------------- K2c: row_ptr + cursor ----------------
__global__ void k_rowptr(const int* __restrict__ deg_in, const int* __restrict__ boff,
                         int* __restrict__ row_ptr, int* __restrict__ cursor) {
    __shared__ int s[256];
    int t = threadIdx.x;
    int i = blockIdx.x * 256 + t;
    int my = (i < N_NODES) ? deg_in[i] : 0;
    s[t] = my;
    __syncthreads();
    for (int o = 1; o < 256; o <<= 1) {
        int v = (t >= o) ? s[t - o] : 0;
        __syncthreads();
        s[t] += v;
        __syncthreads();
    }
    if (i < N_NODES) {
        int e = boff[blockIdx.x] + s[t] - my;
        row_ptr[i] = e;
        cursor[i]  = e;
    }
}

// ---------------- K3: fill CSR adjacency (by dst) ----------------
__global__ void k_fill(const int* __restrict__ src, const int* __restrict__ dst,
                       int* __restrict__ cursor, int* __restrict__ adj) {
    int i = blockIdx.x * blockDim.x + threadIdx.x;
    int stride = gridDim.x * blockDim.x;
    for (; i < N_EDGES; i += stride) {
        int p = atomicAdd(&cursor[dst[i]], 1);
        adj[p] = src[i];
    }
}

// ---------------- K4: h = norm_src * (X @ W1)  [the big one] ----------------
__global__ __launch_bounds__(256)
void k_gemm1(const float* __restrict__ X, const float* __restrict__ W1,
             const int* __restrict__ deg_out, float* __restrict__ h) {
    __shared__ float sf[2 * GROWS * PADK];
    const int t = threadIdx.x;
    const int row_base = blockIdx.x * GROWS;
    const int sub = t >> 4;     // 0..15
    const int kk0 = t & 15;     // fixed k within chunk for staging

    float acc[NH];
#pragma unroll
    for (int j = 0; j < NH; ++j) acc[j] = 0.f;

    float rv[16];
    // prologue: stage chunk 0 into regs (chunk 0 always fully in-range on k)
#pragma unroll
    for (int i = 0; i < 16; ++i) {
        int rg = row_base + i * 16 + sub;
        rg = min(rg, N_NODES - 1);
        rv[i] = X[(size_t)rg * K_IN + kk0];
    }

    for (int c = 0; c < NC; ++c) {
        float* sbuf = sf + (c & 1) * (GROWS * PADK);
        // regs -> LDS
#pragma unroll
        for (int i = 0; i < 16; ++i)
            sbuf[(i * 16 + sub) * PADK + kk0] = rv[i];
        // issue loads for next chunk (in flight across barrier + compute)
        if (c + 1 < NC) {
            const int k0n = (c + 1) * TK;
#pragma unroll
            for (int i = 0; i < 16; ++i) {
                int rg = row_base + i * 16 + sub;
                rg = min(rg, N_NODES - 1);
                int k = k0n + kk0;
                rv[i] = (k < K_IN) ? X[(size_t)rg * K_IN + k] : 0.f;
            }
        }
        __syncthreads();
        // compute chunk c: row = t
        const float* frow = sbuf + t * PADK;
        const int k0 = c * TK;
#pragma unroll
        for (int kk = 0; kk < TK; ++kk) {
            float x = frow[kk];
            int wk = min(k0 + kk, K_IN - 1);        // wave-uniform -> s_load
            const float4* wr = (const float4*)(W1 + wk * NH);
            float4 w0 = wr[0], w1 = wr[1], w2 = wr[2], w3 = wr[3];
            acc[0]  = fmaf(x, w0.x, acc[0]);
            acc[1]  = fmaf(x, w0.y, acc[1]);
            acc[2]  = fmaf(x, w0.z, acc[2]);
            acc[3]  = fmaf(x, w0.w, acc[3]);
            acc[4]  = fmaf(x, w1.x, acc[4]);
            acc[5]  = fmaf(x, w1.y, acc[5]);
            acc[6]  = fmaf(x, w1.z, acc[6]);
            acc[7]  = fmaf(x, w1.w, acc[7]);
            acc[8]  = fmaf(x, w2.x, acc[8]);
            acc[9]  = fmaf(x, w2.y, acc[9]);
            acc[10] = fmaf(x, w2.z, acc[10]);
            acc[11] = fmaf(x, w2.w, acc[11]);
            acc[12] = fmaf(x, w3.x, acc[12]);
            acc[13] = fmaf(x, w3.y, acc[13]);
            acc[14] = fmaf(x, w3.z, acc[14]);
            acc[15] = fmaf(x, w3.w, acc[15]);
        }
    }

    int rg = row_base + t;
    if (rg < N_NODES) {
        float ns = rsqrtf((float)max(deg_out[rg], 1));
        float4* hp = (float4*)(h + (size_t)rg * NH);
        hp[0] = make_float4(acc[0] * ns, acc[1] * ns, acc[2] * ns, acc[3] * ns);
        hp[1] = make_float4(acc[4] * ns, acc[5] * ns, acc[6] * ns, acc[7] * ns);
        hp[2] = make_float4(acc[8] * ns, acc[9] * ns, acc[10] * ns, acc[11] * ns);
        hp[3] = make_float4(acc[12] * ns, acc[13] * ns, acc[14] * ns, acc[15] * ns);
    }
}

// ---------------- K5: gather layer1 + relu + fused (.. @ W2) ----------------
// one wave per node; 16 lanes = feature j, 4 edge slots
__global__ __launch_bounds__(256)
void k_layer1(const float* __restrict__ h, const int* __restrict__ adj,
              const int* __restrict__ row_ptr, const int* __restrict__ deg_in,
              const int* __restrict__ deg_out, const float* __restrict__ W2,
              const float* __restrict__ b1, float* __restrict__ g) {
    const int lane = threadIdx.x & 63;
    const int wid  = threadIdx.x >> 6;
    const int d    = blockIdx.x * 4 + wid;
    if (d >= N_NODES) return;                  // wave-uniform
    const int j = lane & 15, slot = lane >> 4;
    const int start = row_ptr[d];
    const int end   = start + deg_in[d];
    float agg = 0.f;
#pragma unroll 2
    for (int p = start + slot; p < end; p += 4) {
        int s = adj[p];
        agg += h[(size_t)s * NH + j];
    }
    agg += __shfl_xor(agg, 16);
    agg += __shfl_xor(agg, 32);
    float nd = rsqrtf((float)max(end - start, 1));
    float tj = fmaxf(fmaf(agg, nd, b1[j]), 0.f);

    __shared__ float st[4][NH];
    if (slot == 0) st[wid][j] = tj;            // wave-local, no barrier needed
    if (lane < NO) {
        float ns = rsqrtf((float)max(deg_out[d], 1));
        float r = 0.f;
#pragma unroll
        for (int q = 0; q < NH; ++q)
            r = fmaf(st[wid][q], W2[q * NO + lane], r);
        g[(size_t)d * 8 + lane] = ns * r;      // g padded to stride 8
    }
}

// ---------------- K6: gather layer2 -> out ----------------
// one wave per node; 8 lanes = output o (7 used), 8 edge slots
__global__ __launch_bounds__(256)
void k_layer2(const float* __restrict__ g, const int* __restrict__ adj,
              const int* __restrict__ row_ptr, const int* __restrict__ deg_in,
              const float* __restrict__ b2, float* __restrict__ out) {
    const int lane = threadIdx.x & 63;
    const int wid  = threadIdx.x >> 6;
    const int d    = blockIdx.x * 4 + wid;
    if (d >= N_NODES) return;
    const int o = lane & 7, slot = lane >> 3;
    const int start = row_ptr[d];
    const int end   = start + deg_in[d];
    float agg = 0.f;
#pragma unroll 2
    for (int p = start + slot; p < end; p += 8) {
        int s = adj[p];
        agg += g[(size_t)s * 8 + o];           // o==7 reads pad (discarded)
    }
    agg += __shfl_xor(agg, 8);
    agg += __shfl_xor(agg, 16);
    agg += __shfl_xor(agg, 32);
    if (lane < NO) {
        float nd = rsqrtf((float)max(end - start, 1));
        out[(size_t)d * NO + lane] = fmaf(agg, nd, b2[lane]);
    }
}

extern "C" void kernel_launch(void* const* d_in, const int* in_sizes, int n_in,
                              void* d_out, int out_size, void* d_ws, size_t ws_size,
                              hipStream_t stream) {
    const float* X  = (const float*)d_in[0];
    const int*   src = (const int*)d_in[1];
    const int*   dst = (const int*)d_in[2];
    const float* W1 = (const float*)d_in[3];
    const float* b1 = (const float*)d_in[4];
    const float* W2 = (const float*)d_in[5];
    const float* b2 = (const float*)d_in[6];
    float* out = (float*)d_out;

    // workspace layout (all 16B-aligned chunks)
    char* w = (char*)d_ws;
    float* h        = (float*)w;  w += (size_t)N_NODES * NH * 4;   // 6.4 MB
    float* g        = (float*)w;  w += (size_t)N_NODES * 8 * 4;    // 3.2 MB
    int*   adj      = (int*)w;    w += (size_t)N_EDGES * 4;        // 12.8 MB
    int*   deg_out_a= (int*)w;    w += (size_t)N_NODES * 4;
    int*   deg_in_a = (int*)w;    w += (size_t)N_NODES * 4;
    int*   row_ptr  = (int*)w;    w += (size_t)N_NODES * 4;
    int*   cursor   = (int*)w;    w += (size_t)N_NODES * 4;
    int*   bsum     = (int*)w;    w += 512 * 4;
    int*   boff     = (int*)w;    w += 512 * 4;

    // deg_out_a and deg_in_a are contiguous: one memset
    hipMemsetAsync(deg_out_a, 0, (size_t)N_NODES * 2 * 4, stream);

    k_degrees<<<1024, 256, 0, stream>>>(src, dst, deg_out_a, deg_in_a);
    k_bsum  <<<NBLK, 256, 0, stream>>>(deg_in_a, bsum);
    k_scan  <<<1, 512, 0, stream>>>(bsum, boff);
    k_rowptr<<<NBLK, 256, 0, stream>>>(deg_in_a, boff, row_ptr, cursor);
    k_fill  <<<1024, 256, 0, stream>>>(src, dst, cursor, adj);
    k_gemm1 <<<NBLK, 256, 0, stream>>>(X, W1, deg_out_a, h);
    k_layer1<<<(N_NODES + 3) / 4, 256, 0, stream>>>(h, adj, row_ptr, deg_in_a,
                                                    deg_out_a, W2, b1, g);
    k_layer2<<<(N_NODES + 3) / 4, 256, 0, stream>>>(g, adj, row_ptr, deg_in_a,
                                                    b2, out);
}